// Round 7
// baseline (1338.944 us; speedup 1.0000x reference)
//
#include <hip/hip_runtime.h>
#include <hip/hip_fp16.h>
#include <stdint.h>

// ---------------------------------------------------------------------------
// SeqAE: enc LSTM (3->200, T=800, B=256) -> maxpool(T) -> dec LSTM (200->3)
// R7: 1 WG/batch, 1024 thr (16 waves). Wave-group = K-quarter (25 pairs,
// wave-uniform readlane broadcast); slot sigma = (wid&3)*64+lane owns rows
// {sigma, sigma+256, sigma+512}; rows 768..799 tail on wave wid=5*q (one per
// SIMD). w[75]/thread (R6 had 100 incl 22% dummy waste -> AGPR tax halved).
// Single h buffer (phase order makes dbuf unneeded). part[4][832] f32: b32
// writes/reads, conflict-free. Combine on waves 0-3 under s_setprio(1).
// ---------------------------------------------------------------------------

typedef _Float16 half2_t __attribute__((ext_vector_type(2)));

__device__ __forceinline__ float fdot2f(uint32_t hp, uint32_t wp, float acc) {
#if __has_builtin(__builtin_amdgcn_fdot2)
  return __builtin_amdgcn_fdot2(__builtin_bit_cast(half2_t, hp),
                                __builtin_bit_cast(half2_t, wp), acc, false);
#else
  half2_t a = __builtin_bit_cast(half2_t, hp);
  half2_t b = __builtin_bit_cast(half2_t, wp);
  return acc + (float)a[0] * (float)b[0] + (float)a[1] * (float)b[1];
#endif
}

__device__ __forceinline__ float hsig(float z) {
  return fminf(fmaxf(__builtin_fmaf(0.2f, z, 0.5f), 0.f), 1.f);
}

__device__ __forceinline__ float tanh_fast(float v) {
  float e = __builtin_amdgcn_exp2f(v * 2.885390081777927f);
  return 1.f - 2.f * __builtin_amdgcn_rcpf(e + 1.f);
}

// --- pack Whh (800x200 f32, row-major) into f16 pairs, layout wpk[pair][row]
__global__ void prep_kernel(const float* __restrict__ whh,
                            uint32_t* __restrict__ wpk) {
  int idx = blockIdx.x * 256 + threadIdx.x;      // 100 pairs * 800 rows
  if (idx >= 80000) return;
  int p = idx / 800;
  int j = idx - p * 800;
  float a = whh[j * 200 + 2 * p];
  float b = whh[j * 200 + 2 * p + 1];
  __half2 v = __floats2half2_rn(a, b);
  wpk[idx] = __builtin_bit_cast(uint32_t, v);
}

// --- fused encoder + maxpool + decoder: grid 256 (batch), 1024 threads
__global__ __launch_bounds__(1024, 4)
void enc_kernel(const float* __restrict__ x,       // (256,3,800)
                const float* __restrict__ wih,     // (800,3)
                const float* __restrict__ bih,     // (800)
                const float* __restrict__ bhh,     // (800)
                const uint32_t* __restrict__ wpk,  // (100,800) f16 pairs
                const float* __restrict__ dwih,    // (12,200)
                const float* __restrict__ dbih,    // (12)
                const float* __restrict__ dbhh,    // (12)
                const float* __restrict__ dwhh,    // (12,3)
                float* __restrict__ out)           // (256,3,800)
{
  const int b = blockIdx.x;
  const int t = threadIdx.x;
  const int lane = t & 63;
  const int wid = t >> 6;                 // 0..15
  const int q2 = wid >> 2;                // K-quarter 0..3 (wave-uniform)
  const int slot = (wid & 3) * 64 + lane; // 0..255
  const bool istail = (wid == q2 * 5);    // wid 0,5,10,15 -> SIMD 0,1,2,3

  __shared__ uint32_t hbuf[112];          // h f16 pairs; quarter q at dw 28q
  __shared__ uint2 xs2[800];              // (pk(x0,x1), pk(x2,0))
  __shared__ float part[4][832];          // partials, [quarter][row]
  __shared__ float hist[3200];            // decoder history [800][4]
  __shared__ float pooled[200];
  __shared__ float pre12s[12];
  __shared__ int s_tc;

  // ---- staging ----
  {
    const float* xb = x + (size_t)b * 2400;
    if (t < 800) {
      __half2 p01 = __floats2half2_rn(xb[t], xb[800 + t]);
      __half2 p23 = __floats2half2_rn(xb[1600 + t], 0.f);
      uint2 v;
      v.x = __builtin_bit_cast(uint32_t, p01);
      v.y = __builtin_bit_cast(uint32_t, p23);
      xs2[t] = v;
    }
    if (t < 112) hbuf[t] = 0;
  }

  // ---- resident weights: 3 rows x 25 pairs (this wave's K-quarter) ----
  const int r1 = slot, r2 = slot + 256, r3 = slot + 512;
  uint32_t w[75];
  {
    const uint32_t* src = wpk + (size_t)(q2 * 25) * 800;
#pragma unroll
    for (int p = 0; p < 25; ++p) {
      w[p]      = src[p * 800 + r1];
      w[25 + p] = src[p * 800 + r2];
      w[50 + p] = src[p * 800 + r3];
    }
  }
#pragma unroll
  for (int i = 0; i < 75; ++i) asm volatile("" : "+v"(w[i]));

  // tail rows 768..799: wave wid==5*q2, lanes 0..31 own row 768+lane
  uint32_t w4[25];
  const int r4 = 768 + (lane & 31);
  if (istail) {
    const uint32_t* src = wpk + (size_t)(q2 * 25) * 800;
#pragma unroll
    for (int p = 0; p < 25; ++p) w4[p] = src[p * 800 + r4];
#pragma unroll
    for (int i = 0; i < 25; ++i) asm volatile("" : "+v"(w4[i]));
  }

  // step-invariants: q==1 carries bias, q==2 carries packed f16 Wih
  float bias1 = 0.f, bias2 = 0.f, bias3 = 0.f, bias4 = 0.f;
  uint32_t wiv[6], wiv4[2];
  if (q2 == 1) {
    bias1 = bih[r1] + bhh[r1];
    bias2 = bih[r2] + bhh[r2];
    bias3 = bih[r3] + bhh[r3];
    if (istail) bias4 = bih[r4] + bhh[r4];
  }
  if (q2 == 2) {
    const int rr[3] = {r1, r2, r3};
#pragma unroll
    for (int c = 0; c < 3; ++c) {
      __half2 a = __floats2half2_rn(wih[rr[c] * 3 + 0], wih[rr[c] * 3 + 1]);
      __half2 bq = __floats2half2_rn(wih[rr[c] * 3 + 2], 0.f);
      wiv[2 * c]     = __builtin_bit_cast(uint32_t, a);
      wiv[2 * c + 1] = __builtin_bit_cast(uint32_t, bq);
    }
    __half2 a = __floats2half2_rn(wih[r4 * 3 + 0], wih[r4 * 3 + 1]);
    __half2 bq = __floats2half2_rn(wih[r4 * 3 + 2], 0.f);
    wiv4[0] = __builtin_bit_cast(uint32_t, a);
    wiv4[1] = __builtin_bit_cast(uint32_t, bq);
  } else {
#pragma unroll
    for (int j = 0; j < 6; ++j) wiv[j] = 0;
    wiv4[0] = wiv4[1] = 0;
  }

  float c_state = 0.f;
  float maxh = -INFINITY;

  const int lidx = (lane < 7) ? lane : 6;  // b128 covers 28 dw >= 25 pairs
  const uint4* hq = (const uint4*)&hbuf[q2 * 28];

  __syncthreads();

  for (int step = 0; step < 800; ++step) {
    uint4 hv = hq[lidx];
    float a1, a2, a3;
    if (q2 == 1) { a1 = bias1; a2 = bias2; a3 = bias3; }
    else { a1 = a2 = a3 = 0.f; }
#pragma unroll
    for (int p = 0; p < 25; ++p) {
      const int ln = p >> 2, d = p & 3;
      uint32_t comp = (d == 0) ? hv.x : (d == 1) ? hv.y : (d == 2) ? hv.z : hv.w;
      uint32_t hp = __builtin_amdgcn_readlane(comp, ln);
      a1 = fdot2f(hp, w[p], a1);
      a2 = fdot2f(hp, w[25 + p], a2);
      a3 = fdot2f(hp, w[50 + p], a3);
    }
    if (q2 == 2) {
      uint2 xv = xs2[step];
      a1 = fdot2f(xv.y, wiv[1], fdot2f(xv.x, wiv[0], a1));
      a2 = fdot2f(xv.y, wiv[3], fdot2f(xv.x, wiv[2], a2));
      a3 = fdot2f(xv.y, wiv[5], fdot2f(xv.x, wiv[4], a3));
    }
    part[q2][r1] = a1;
    part[q2][r2] = a2;
    part[q2][r3] = a3;
    if (istail) {
      float a4 = (q2 == 1) ? bias4 : 0.f;
#pragma unroll
      for (int p = 0; p < 25; ++p) {
        const int ln = p >> 2, d = p & 3;
        uint32_t comp = (d == 0) ? hv.x : (d == 1) ? hv.y : (d == 2) ? hv.z : hv.w;
        uint32_t hp = __builtin_amdgcn_readlane(comp, ln);
        a4 = fdot2f(hp, w4[p], a4);
      }
      if (q2 == 2) {
        uint2 xv = xs2[step];
        a4 = fdot2f(xv.y, wiv4[1], fdot2f(xv.x, wiv4[0], a4));
      }
      if (lane < 32) part[q2][r4] = a4;
    }
    __syncthreads();
    if (t < 200) {                         // combiners: waves 0-3
      __builtin_amdgcn_s_setprio(1);
      const int u = t;
      float gi = part[0][u]       + part[1][u]       + part[2][u]       + part[3][u];
      float gf = part[0][u + 200] + part[1][u + 200] + part[2][u + 200] + part[3][u + 200];
      float gg = part[0][u + 400] + part[1][u + 400] + part[2][u + 400] + part[3][u + 400];
      float go = part[0][u + 600] + part[1][u + 600] + part[2][u + 600] + part[3][u + 600];
      float i_ = hsig(gi), f_ = hsig(gf), o_ = hsig(go);
      float g_ = tanh_fast(gg);
      c_state = __builtin_fmaf(f_, c_state, i_ * g_);
      float h_ = o_ * tanh_fast(c_state);
      maxh = fmaxf(maxh, h_);
      const int pp = u >> 1, qq = pp / 25, loc = pp - 25 * qq;
      ((__half*)hbuf)[(28 * qq + loc) * 2 + (u & 1)] = __float2half(h_);
      __builtin_amdgcn_s_setprio(0);
    }
    __syncthreads();
  }

  // ---- maxpool -> decoder constant input pre12 ----
  if (t < 200) pooled[t] = maxh;
  __syncthreads();
  if (t < 12) {
    float s = dbih[t] + dbhh[t];
    const float* wr = dwih + t * 200;
#pragma unroll 8
    for (int uu = 0; uu < 200; ++uu) s = __builtin_fmaf(pooled[uu], wr[uu], s);
    pre12s[t] = s;
  }
  __syncthreads();

  // ---- decoder: lanes 0..2, 6-dim recurrence, bitwise fixed-point exit ----
  if (t < 3) {
    float pre[12];
#pragma unroll
    for (int j = 0; j < 12; ++j) pre[j] = pre12s[j];
    float W[36];
#pragma unroll
    for (int j = 0; j < 36; ++j) W[j] = dwhh[j];

    float h0 = 0, h1 = 0, h2 = 0, c0 = 0, c1 = 0, c2 = 0;
    int tc = 800;
    for (int step = 0; step < 800; ++step) {
      float g[12];
#pragma unroll
      for (int j = 0; j < 12; ++j) {
        float v = pre[j];
        v = __builtin_fmaf(W[j * 3 + 0], h0, v);
        v = __builtin_fmaf(W[j * 3 + 1], h1, v);
        v = __builtin_fmaf(W[j * 3 + 2], h2, v);
        g[j] = v;
      }
      float nc0 = hsig(g[3]) * c0 + hsig(g[0]) * tanh_fast(g[6]);
      float nc1 = hsig(g[4]) * c1 + hsig(g[1]) * tanh_fast(g[7]);
      float nc2 = hsig(g[5]) * c2 + hsig(g[2]) * tanh_fast(g[8]);
      float nh0 = hsig(g[9])  * tanh_fast(nc0);
      float nh1 = hsig(g[10]) * tanh_fast(nc1);
      float nh2 = hsig(g[11]) * tanh_fast(nc2);
      bool same = (nh0 == h0) && (nh1 == h1) && (nh2 == h2) &&
                  (nc0 == c0) && (nc1 == c1) && (nc2 == c2);
      float mine = (t == 0) ? nh0 : ((t == 1) ? nh1 : nh2);
      hist[step * 4 + t] = mine;
      h0 = nh0; h1 = nh1; h2 = nh2; c0 = nc0; c1 = nc1; c2 = nc2;
      if (same) { tc = step + 1; break; }       // exact fixed point
    }
    if (t == 0) s_tc = tc;
  }
  __syncthreads();

  // ---- coalesced writeback: out[b, f, tt] = hist[f][min(tt, tc-1)] ----
  {
    const int tcv = s_tc, tc1 = tcv - 1;
    float* ob = out + (size_t)b * 2400;
    if (t < 800) {
      int idx = (t < tcv) ? t : tc1;
      ob[t]        = hist[idx * 4 + 0];
      ob[800 + t]  = hist[idx * 4 + 1];
      ob[1600 + t] = hist[idx * 4 + 2];
    }
  }
}

extern "C" void kernel_launch(void* const* d_in, const int* in_sizes, int n_in,
                              void* d_out, int out_size, void* d_ws, size_t ws_size,
                              hipStream_t stream)
{
  const float* x    = (const float*)d_in[0];
  const float* wih  = (const float*)d_in[1];
  const float* whh  = (const float*)d_in[2];
  const float* bih  = (const float*)d_in[3];
  const float* bhh  = (const float*)d_in[4];
  const float* dwih = (const float*)d_in[5];
  const float* dwhh = (const float*)d_in[6];
  const float* dbih = (const float*)d_in[7];
  const float* dbhh = (const float*)d_in[8];
  float* out = (float*)d_out;

  uint32_t* wpk = (uint32_t*)d_ws;   // 320000 B

  hipLaunchKernelGGL(prep_kernel, dim3(313), dim3(256), 0, stream, whh, wpk);
  hipLaunchKernelGGL(enc_kernel, dim3(256), dim3(1024), 0, stream,
                     x, wih, bih, bhh, wpk, dwih, dbih, dbhh, dwhh, out);
}